// Round 11
// baseline (29.127 us; speedup 1.0000x reference)
//
#include <hip/hip_runtime.h>

#define NT   256
#define NBLK 512
#define PPI  (NBLK * NT / 4)   // problems per pipeline iteration = 32768

// ============================================================================
// Persistent pipelined kernel. 4 lanes per problem (quad slot q = tid&3 owns
// global rows {2q,2q+1}); DPP quad_perm broadcasts; packed v_pk_fma_f32.
// Each thread handles NI problems (grid-stride by PPI). The NEXT problem's A
// (12 KB/wave) is prefetched into a per-wave-private LDS stage buffer with
// global_load_lds (direct-to-LDS, zero VGPR payload) issued BEFORE the
// current problem's ~2000-cycle compute chain -> memory overlaps compute.
//
// R11 hardening vs the NaN R10: every global_load_lds uses offset=0 (the ISA
// ambiguity of whether the instr offset also biases the LDS address cannot
// bite); chunk displacement is carried in the per-lane global pointer AND the
// LDS slot pointer. Explicit lgkmcnt(0)+sched_barrier after stage consumption
// before re-issuing DMAs into the same slots.
//
// LDS 64KB/block -> 2 blocks/CU -> 2 waves/SIMD. Stage buffer is wave-private,
// a3 slot thread-private -> no __syncthreads anywhere.
// ============================================================================

typedef float v2f __attribute__((ext_vector_type(2)));

template <int O>
__device__ __forceinline__ float qb(float x) {
    return __int_as_float(__builtin_amdgcn_mov_dpp(
        __float_as_int(x), O * 0x55, 0xF, 0xF, true));
}
template <int O>
__device__ __forceinline__ v2f qb2(v2f y) {
    v2f r;
    r.x = qb<O>(y.x);
    r.y = qb<O>(y.y);
    return r;
}
__device__ __forceinline__ v2f pkfma(v2f a, v2f b, v2f c) {
    return __builtin_elementwise_fma(a, b, c);   // -> v_pk_fma_f32
}

// acc(2x8, col-pairs) += SGN * X(2x8) @ Y, contribution from Y's global rows
// {2O, 2O+1} (held by quad slot O as its local rows 0,1).
template <int SGN, int O>
__device__ __forceinline__ void mm4_o(v2f (&acc)[8], const v2f (&X)[8],
                                      const v2f (&Y)[8]) {
#pragma unroll
    for (int s = 0; s < 2; ++s) {            // global k = 2O + s
        v2f w2[4];
#pragma unroll
        for (int jj = 0; jj < 4; ++jj) w2[jj] = qb2<O>(Y[s * 4 + jj]);
#pragma unroll
        for (int r = 0; r < 2; ++r) {
            const float x0 = (s == 0) ? X[r * 4 + O].x : X[r * 4 + O].y;
            const float xs = (SGN > 0) ? x0 : -x0;
            const v2f xx = {xs, xs};
#pragma unroll
            for (int jj = 0; jj < 4; ++jj)
                acc[r * 4 + jj] = pkfma(xx, w2[jj], acc[r * 4 + jj]);
        }
    }
}
template <int SGN>
__device__ __forceinline__ void mm4(v2f (&acc)[8], const v2f (&X)[8],
                                    const v2f (&Y)[8]) {
    mm4_o<SGN, 0>(acc, X, Y);
    mm4_o<SGN, 1>(acc, X, Y);
    mm4_o<SGN, 2>(acc, X, Y);
    mm4_o<SGN, 3>(acc, X, Y);
}

// One DMA chunk: 64 lanes x 16B -> LDS slot (lane-linear), offset literal 0.
__device__ __forceinline__ void glds1(const float4* g, float4* l) {
    __builtin_amdgcn_global_load_lds(
        (const __attribute__((address_space(1))) void*)g,
        (__attribute__((address_space(3))) void*)l,
        16, 0, 0);
}

// Stage all 12 chunks of this wave's next 16 problems.
// g = A4 + p*48 + q*4 (per-lane); slot m*4+c <- g + m*16 + c.
__device__ __forceinline__ void stage_all(const float4* g, float4* l) {
    glds1(g + 0,  l + 0 * 64);   glds1(g + 1,  l + 1 * 64);
    glds1(g + 2,  l + 2 * 64);   glds1(g + 3,  l + 3 * 64);
    glds1(g + 16, l + 4 * 64);   glds1(g + 17, l + 5 * 64);
    glds1(g + 18, l + 6 * 64);   glds1(g + 19, l + 7 * 64);
    glds1(g + 32, l + 8 * 64);   glds1(g + 33, l + 9 * 64);
    glds1(g + 34, l + 10 * 64);  glds1(g + 35, l + 11 * 64);
}

__global__ __launch_bounds__(NT)
void magnus6_kernel(const float* __restrict__ A,
                    const float* __restrict__ hp,
                    const float* __restrict__ y0,
                    float* __restrict__ out,
                    int B, int NI)
{
    __shared__ float4 stage[4][12][64];   // per-wave stage buffers, 48 KB
    __shared__ float4 a3s[4][NT];         // per-thread alpha3 slot, 16 KB

    const int tx    = threadIdx.x;
    const int w     = tx >> 6;            // wave in block
    const int lane  = tx & 63;
    const int q     = tx & 3;             // quad slot: owns rows 2q, 2q+1
    const int pslot = blockIdx.x * (NT / 4) + (tx >> 2);

    const float h    = hp[0];
    const float c_a2 = h * 1.2909944487358056f;   // h*sqrt(15)/3
    const float c_a3 = h * (10.0f / 3.0f);
    const float c_m  = 20.0f / 3.0f;

    const float4* __restrict__ A4 = reinterpret_cast<const float4*>(A);
    float4* sb = &stage[w][0][0];

    // ---- prologue: stage iteration 0 ----
    {
        const int pn = pslot;
        const int pc = pn < B ? pn : B - 1;
        stage_all(A4 + (size_t)pc * 48 + q * 4, sb);
    }

    for (int n = 0; n < NI; ++n) {
        const int p   = n * PPI + pslot;
        const int pcl = p < B ? p : B - 1;

        // wait for this iteration's staged data; fence per rule 18
        asm volatile("s_waitcnt vmcnt(0)" ::: "memory");
        __builtin_amdgcn_sched_barrier(0);

        const float2 y0v =
            *reinterpret_cast<const float2*>(y0 + (size_t)pcl * 8 + 2 * q);

        v2f R1[8];   // alpha1 -> Omega0 -> Omega
        v2f R2[8];   // alpha2 -> Q
        v2f R3[8];   // C1 -> T' -> P'

        // ---- alpha build from staged LDS ----
#pragma unroll
        for (int c = 0; c < 4; ++c) {
            float4 v1 = stage[w][c][lane];
            float4 v2 = stage[w][4 + c][lane];
            float4 v3 = stage[w][8 + c][lane];
            const int b = (c >> 1) * 4 + (c & 1) * 2;
            v2f A1lo = {v1.x, v1.y}, A1hi = {v1.z, v1.w};
            v2f A2lo = {v2.x, v2.y}, A2hi = {v2.z, v2.w};
            v2f A3lo = {v3.x, v3.y}, A3hi = {v3.z, v3.w};
            v2f al1lo = h * A2lo, al1hi = h * A2hi;            // alpha1
            R1[b] = al1lo; R1[b + 1] = al1hi;
            R2[b]     = c_a2 * (A3lo - A1lo);                  // alpha2
            R2[b + 1] = c_a2 * (A3hi - A1hi);
            v2f a3lo = c_a3 * (A1lo + A3lo) - c_m * al1lo;     // alpha3
            v2f a3hi = c_a3 * (A1hi + A3hi) - c_m * al1hi;
            a3s[c][tx] = make_float4(a3lo.x, a3lo.y, a3hi.x, a3hi.y);
        }

        // ---- drain LDS reads, then issue next iteration's staging BEFORE
        //      the compute chain (same slots; now provably consumed) ----
        asm volatile("s_waitcnt lgkmcnt(0)" ::: "memory");
        __builtin_amdgcn_sched_barrier(0);
        if (n + 1 < NI) {
            const int pn = (n + 1) * PPI + pslot;
            const int pc = pn < B ? pn : B - 1;
            stage_all(A4 + (size_t)pc * 48 + q * 4, sb);
        }
        __builtin_amdgcn_sched_barrier(0);

        // ---- C1 = [alpha1, alpha2] into R3 ----
#pragma unroll
        for (int i = 0; i < 8; ++i) R3[i] = (v2f){0.0f, 0.0f};
        mm4<+1>(R3, R1, R2);
        mm4<-1>(R3, R2, R1);

        // ---- T' = (C1 + 2*alpha3)/60 ----
#pragma unroll
        for (int c = 0; c < 4; ++c) {
            float4 v = a3s[c][tx];
            v2f a3lo = {v.x, v.y}, a3hi = {v.z, v.w};
            const int b = (c >> 1) * 4 + (c & 1) * 2;
            const v2f k60 = {1.0f / 60.0f, 1.0f / 60.0f};
            R3[b]     = pkfma(R3[b],     k60, (1.0f / 30.0f) * a3lo);
            R3[b + 1] = pkfma(R3[b + 1], k60, (1.0f / 30.0f) * a3hi);
        }

        // ---- Q = alpha2 - alpha1@T' + T'@alpha1 ----
        mm4<-1>(R2, R1, R3);
        mm4<+1>(R2, R3, R1);

        // ---- P' (R3); Omega0 (R1) ----
#pragma unroll
        for (int c = 0; c < 4; ++c) {
            float4 v = a3s[c][tx];
            v2f a3lo = {v.x, v.y}, a3hi = {v.z, v.w};
            const int b = (c >> 1) * 4 + (c & 1) * 2;
            v2f t0 = R3[b], t1 = R3[b + 1];
            v2f a10 = R1[b], a11 = R1[b + 1];
            R3[b]     = 0.25f * t0 - (1.0f / 12.0f) * a10 - (1.0f / 80.0f) * a3lo;
            R3[b + 1] = 0.25f * t1 - (1.0f / 12.0f) * a11 - (1.0f / 80.0f) * a3hi;
            R1[b]     = a10 + (1.0f / 12.0f) * a3lo;
            R1[b + 1] = a11 + (1.0f / 12.0f) * a3hi;
        }

        // ---- Omega = Omega0 + P'@Q - Q@P' ----
        mm4<+1>(R1, R3, R2);
        mm4<-1>(R1, R2, R3);

        // ---- y = expm(Omega) @ y0, Taylor order 6 ----
        float v0 = y0v.x, v1 = y0v.y;
        float yy0 = v0, yy1 = v1;
        const float inv[6] = {1.0f, 0.5f, 1.0f / 3.0f, 0.25f, 0.2f, 1.0f / 6.0f};
#pragma unroll
        for (int k = 0; k < 6; ++k) {
            v2f acc0 = {0.0f, 0.0f}, acc1 = {0.0f, 0.0f};
            v2f vw;
            vw.x = qb<0>(v0); vw.y = qb<0>(v1);
            acc0 = pkfma(R1[0], vw, acc0); acc1 = pkfma(R1[4], vw, acc1);
            vw.x = qb<1>(v0); vw.y = qb<1>(v1);
            acc0 = pkfma(R1[1], vw, acc0); acc1 = pkfma(R1[5], vw, acc1);
            vw.x = qb<2>(v0); vw.y = qb<2>(v1);
            acc0 = pkfma(R1[2], vw, acc0); acc1 = pkfma(R1[6], vw, acc1);
            vw.x = qb<3>(v0); vw.y = qb<3>(v1);
            acc0 = pkfma(R1[3], vw, acc0); acc1 = pkfma(R1[7], vw, acc1);
            v0 = (acc0.x + acc0.y) * inv[k];
            v1 = (acc1.x + acc1.y) * inv[k];
            yy0 += v0;
            yy1 += v1;
        }

        if (p < B)
            *reinterpret_cast<float2*>(out + (size_t)p * 8 + 2 * q) =
                make_float2(yy0, yy1);
    }
}

extern "C" void kernel_launch(void* const* d_in, const int* in_sizes, int n_in,
                              void* d_out, int out_size, void* d_ws, size_t ws_size,
                              hipStream_t stream)
{
    const float* A  = (const float*)d_in[0];
    const float* hp = (const float*)d_in[1];
    const float* y0 = (const float*)d_in[2];
    float* out = (float*)d_out;

    const int B  = in_sizes[2] / 8;          // y0 is (B, 8)
    const int NI = (B + PPI - 1) / PPI;      // pipeline iterations per thread
    magnus6_kernel<<<NBLK, NT, 0, stream>>>(A, hp, y0, out, B, NI);
}